// Round 2
// baseline (1258.953 us; speedup 1.0000x reference)
//
#include <hip/hip_runtime.h>
#include <hip/hip_bf16.h>

#define Bn 4
#define C1n 256
#define C2n 128
#define CF 384
#define HWn 65536
#define Kc 128
#define Nn 512          // B*K
#define En 256
#define NCn 16
#define Gn 512
#define Rn 64
#define HEADSn 8
#define DHn 32

#define TCg 64          // channels per segreduce block
#define TPg 64          // pixels per tile
#define PCH 2048        // pixels per chunk (per block)

// ---------------- zero workspace accumulators ----------------
__global__ void zero_k(float* __restrict__ p, int n) {
    int i = blockIdx.x * 256 + threadIdx.x;
    if (i < n) p[i] = 0.f;
}

// ---------------- area histogram: one block per batch ----------------
__global__ void area_k(const int* __restrict__ mask, float* __restrict__ areaf,
                       float* __restrict__ area_out) {
    int b = blockIdx.x;
    __shared__ int hist[132];
    for (int i = threadIdx.x; i < 132; i += blockDim.x) hist[i] = 0;
    __syncthreads();
    const int* mp = mask + (size_t)b * HWn;
    for (int px = threadIdx.x * 4; px < HWn; px += blockDim.x * 4) {
        int4 id = *(const int4*)(mp + px);
        atomicAdd(&hist[id.x], 1);
        atomicAdd(&hist[id.y], 1);
        atomicAdd(&hist[id.z], 1);
        atomicAdd(&hist[id.w], 1);
    }
    __syncthreads();
    int t = threadIdx.x;
    if (t >= 1 && t <= Kc) {
        float a = (float)hist[t];
        areaf[b * Kc + t - 1] = a;
        area_out[b * Kc + t - 1] = a;
    }
}

// ---------------- transposed segment reduce ----------------
// grid (32 chunks, 6 chan-groups, 4 batches), 256 threads.
// LDS tile transpose: load lanes-along-pixels (coalesced global), accumulate
// lanes-along-channels (uniform seg id per wave-instr -> conflict-free LDS atomics).
__global__ __launch_bounds__(256) void segreduce2_k(
        const float* __restrict__ hd1, const float* __restrict__ h1,
        const int* __restrict__ mask,
        float* __restrict__ sums, float* __restrict__ bg) {
    int chunk = blockIdx.x, cg = blockIdx.y, b = blockIdx.z;
    int c0 = cg * TCg;
    const float* base = (c0 < C1n)
        ? hd1 + ((size_t)(b * C1n + c0)) * HWn
        : h1  + ((size_t)(b * C2n + (c0 - C1n))) * HWn;
    const int* mp = mask + (size_t)b * HWn + chunk * PCH;

    __shared__ float tile[TPg * 65];      // [pixel][channel], pad 65
    __shared__ float bins[129 * TCg];     // [cell][channel]
    __shared__ int   idsh[TPg];

    int t = threadIdx.x, w = t >> 6, l = t & 63;
    for (int i = t; i < 129 * TCg; i += 256) bins[i] = 0.f;
    __syncthreads();

    for (int tl = 0; tl < PCH / TPg; ++tl) {
        int px0 = tl * TPg;
        if (w == 0) idsh[l] = mp[px0 + l];
        #pragma unroll
        for (int cc = 0; cc < 16; ++cc) {
            int c = cc * 4 + w;                    // wave w loads channels w,4+w,...
            tile[l * 65 + c] = base[(size_t)c * HWn + px0 + l];   // 256B coalesced
        }
        __syncthreads();
        #pragma unroll
        for (int pp = 0; pp < 16; ++pp) {
            int p = w * 16 + pp;
            int id = idsh[p];                      // wave-uniform
            atomicAdd(&bins[id * TCg + l], tile[p * 65 + l]);  // consecutive addrs
        }
        __syncthreads();
    }
    // flush partials: coalesced global atomics (64-aligned runs per wave)
    for (int i = t; i < 129 * TCg; i += 256) {
        int cell = i / TCg, c = c0 + (i % TCg);
        float v = bins[i];
        if (cell == 0) atomicAdd(&bg[b * CF + c], v);
        else atomicAdd(&sums[((size_t)(b * Kc + cell - 1)) * CF + c], v);
    }
}

// ---------------- glob = plane mean = (cells + background)/HW ----------------
__global__ void glob_k(const float* __restrict__ sums, const float* __restrict__ bg,
                       float* __restrict__ glob) {
    int idx = blockIdx.x * 256 + threadIdx.x;
    if (idx >= Bn * CF) return;
    int b = idx / CF, c = idx % CF;
    float s = bg[idx];
    for (int cell = 0; cell < Kc; ++cell)
        s += sums[((size_t)(b * Kc + cell)) * CF + c];
    glob[idx] = s * (1.f / (float)HWn);
}

// ---------------- emb GEMM: A built on the fly, [512,768]x[768,256] ----------------
__global__ void gemm_emb_k(const float* __restrict__ sums, const float* __restrict__ glob,
                           const float* __restrict__ areaf, const float* __restrict__ Bw,
                           float* __restrict__ C) {
    const int R = 4, K = 768, N = 256;
    int row0 = blockIdx.x * R;
    __shared__ float As[R * K];
    __shared__ float rina[R];
    if (threadIdx.x < R) {
        float a = areaf[row0 + threadIdx.x];
        rina[threadIdx.x] = 1.f / fmaxf(a, 1.f);
    }
    __syncthreads();
    for (int idx = threadIdx.x; idx < R * K; idx += blockDim.x) {
        int r = idx / K, k = idx % K;
        int row = row0 + r;
        float v;
        if (k < CF) v = sums[(size_t)row * CF + k] * rina[r];
        else        v = glob[(row >> 7) * CF + (k - CF)];
        As[r * K + k] = v;
    }
    __syncthreads();
    int j = threadIdx.x;
    float acc[R] = {0.f, 0.f, 0.f, 0.f};
    const float* bp = Bw + j;
    #pragma unroll 8
    for (int k = 0; k < K; k++) {
        float bv = bp[(size_t)k * N];
        #pragma unroll
        for (int r = 0; r < R; r++) acc[r] = fmaf(As[r * K + k], bv, acc[r]);
    }
    #pragma unroll
    for (int r = 0; r < R; r++) C[(size_t)(row0 + r) * N + j] = acc[r];
}

// ---------------- per-batch mean of emb over K cells ----------------
__global__ void patch_mean_k(const float* __restrict__ emb, float* __restrict__ ep) {
    int b = blockIdx.x, j = threadIdx.x;
    float s = 0.f;
    for (int r = 0; r < Kc; r++) s += emb[(size_t)(b * Kc + r) * En + j];
    ep[b * En + j] = s * (1.f / (float)Kc);
}

// ---------------- comp MLP + softmax: one block per batch ----------------
__global__ void comp_mlp_k(const float* __restrict__ ep, const float* __restrict__ w1,
                           const float* __restrict__ w2, float* __restrict__ comp_ws,
                           float* __restrict__ comp_out) {
    int b = blockIdx.x, j = threadIdx.x;
    __shared__ float h[En];
    __shared__ float c[NCn];
    float acc = 0.f;
    #pragma unroll 8
    for (int k = 0; k < En; k++) acc = fmaf(ep[b * En + k], w1[(size_t)k * En + j], acc);
    h[j] = fmaxf(acc, 0.f);
    __syncthreads();
    if (j < NCn) {
        float a2 = 0.f;
        #pragma unroll 8
        for (int k = 0; k < En; k++) a2 = fmaf(h[k], w2[(size_t)k * NCn + j], a2);
        c[j] = a2;
    }
    __syncthreads();
    if (j == 0) {
        float m = c[0];
        for (int t = 1; t < NCn; t++) m = fmaxf(m, c[t]);
        float s = 0.f;
        for (int t = 0; t < NCn; t++) { c[t] = __expf(c[t] - m); s += c[t]; }
        float inv = 1.f / s;
        for (int t = 0; t < NCn; t++) c[t] *= inv;
    }
    __syncthreads();
    if (j < NCn) {
        comp_ws[b * NCn + j] = c[j];
        comp_out[b * NCn + j] = c[j];
    }
}

// ---------------- fused hist: out_ct = relu(emb@w1)@w2 ----------------
__global__ void fused_hist_k(const float* __restrict__ emb, const float* __restrict__ w1,
                             const float* __restrict__ w2, float* __restrict__ out) {
    int row0 = blockIdx.x * 4;
    __shared__ float As[4 * En];
    __shared__ float Hs[4 * En];
    int j = threadIdx.x;
    for (int idx = j; idx < 4 * En; idx += 256)
        As[idx] = emb[(size_t)row0 * En + idx];
    __syncthreads();
    float acc[4] = {0.f, 0.f, 0.f, 0.f};
    #pragma unroll 8
    for (int k = 0; k < En; k++) {
        float bv = w1[(size_t)k * En + j];
        #pragma unroll
        for (int r = 0; r < 4; r++) acc[r] = fmaf(As[r * En + k], bv, acc[r]);
    }
    #pragma unroll
    for (int r = 0; r < 4; r++) Hs[r * En + j] = fmaxf(acc[r], 0.f);
    __syncthreads();
    if (j < NCn) {
        float a2[4] = {0.f, 0.f, 0.f, 0.f};
        #pragma unroll 8
        for (int k = 0; k < En; k++) {
            float bv = w2[(size_t)k * NCn + j];
            #pragma unroll
            for (int r = 0; r < 4; r++) a2[r] = fmaf(Hs[r * En + k], bv, a2[r]);
        }
        #pragma unroll
        for (int r = 0; r < 4; r++) out[(size_t)(row0 + r) * NCn + j] = a2[r];
    }
}

// ---------------- fused branch: relu(emb@w1)@w2 -> softmax -> @ref ----------------
// grid (128 strips, 3 branches), 256 threads
__global__ void fused_branch_k(const float* __restrict__ emb,
                               const float* __restrict__ wref_w1,
                               const float* __restrict__ wref_w2,
                               const float* __restrict__ ref,
                               float* __restrict__ refw) {
    int i = blockIdx.y;
    int row0 = blockIdx.x * 4;
    const float* w1 = wref_w1 + (size_t)i * En * En;
    const float* w2 = wref_w2 + (size_t)i * En * Rn;
    __shared__ float As[4 * En];
    __shared__ float Hs[4 * En];
    __shared__ float RWs[4][Rn];
    int j = threadIdx.x;
    for (int idx = j; idx < 4 * En; idx += 256)
        As[idx] = emb[(size_t)row0 * En + idx];
    __syncthreads();
    {
        float acc[4] = {0.f, 0.f, 0.f, 0.f};
        #pragma unroll 8
        for (int k = 0; k < En; k++) {
            float bv = w1[(size_t)k * En + j];
            #pragma unroll
            for (int r = 0; r < 4; r++) acc[r] = fmaf(As[r * En + k], bv, acc[r]);
        }
        #pragma unroll
        for (int r = 0; r < 4; r++) Hs[r * En + j] = fmaxf(acc[r], 0.f);
    }
    __syncthreads();
    if (j < Rn) {
        float acc[4] = {0.f, 0.f, 0.f, 0.f};
        #pragma unroll 8
        for (int k = 0; k < En; k++) {
            float bv = w2[(size_t)k * Rn + j];
            #pragma unroll
            for (int r = 0; r < 4; r++) acc[r] = fmaf(Hs[r * En + k], bv, acc[r]);
        }
        #pragma unroll
        for (int r = 0; r < 4; r++) RWs[r][j] = acc[r];
    }
    __syncthreads();
    {   // softmax: wave w handles row w
        int r = j >> 6, l = j & 63;
        float v = RWs[r][l];
        float m = v;
        #pragma unroll
        for (int o = 32; o > 0; o >>= 1) m = fmaxf(m, __shfl_xor(m, o));
        float e = __expf(v - m);
        float s = e;
        #pragma unroll
        for (int o = 32; o > 0; o >>= 1) s += __shfl_xor(s, o);
        RWs[r][l] = e / s;
    }
    __syncthreads();
    {   // refw strip = RWs @ ref  [4 x 512], K=64; each thread 2 cols
        float a0[4] = {0.f, 0.f, 0.f, 0.f}, a1[4] = {0.f, 0.f, 0.f, 0.f};
        #pragma unroll 8
        for (int k = 0; k < Rn; k++) {
            float b0 = ref[(size_t)k * Gn + j];
            float b1 = ref[(size_t)k * Gn + j + 256];
            #pragma unroll
            for (int r = 0; r < 4; r++) {
                a0[r] = fmaf(RWs[r][k], b0, a0[r]);
                a1[r] = fmaf(RWs[r][k], b1, a1[r]);
            }
        }
        float* op = refw + ((size_t)i * Nn + row0) * Gn;
        #pragma unroll
        for (int r = 0; r < 4; r++) {
            op[(size_t)r * Gn + j] = a0[r];
            op[(size_t)r * Gn + j + 256] = a1[r];
        }
    }
}

// ---------------- fused K/V projections: refw strip -> kws & vws ----------------
__global__ void fused_kv_k(const float* __restrict__ refw,
                           const float* __restrict__ ca_wk, const float* __restrict__ ca_wv,
                           float* __restrict__ kws, float* __restrict__ vws) {
    int i = blockIdx.y;
    int row0 = blockIdx.x * 4;
    const float* wk = ca_wk + (size_t)i * Gn * En;
    const float* wv = ca_wv + (size_t)i * Gn * En;
    __shared__ float Rs[4 * Gn];
    int j = threadIdx.x;
    const float* rp = refw + ((size_t)i * Nn + row0) * Gn;
    for (int idx = j; idx < 4 * Gn; idx += 256) Rs[idx] = rp[idx];
    __syncthreads();
    float ak[4] = {0.f, 0.f, 0.f, 0.f}, av[4] = {0.f, 0.f, 0.f, 0.f};
    #pragma unroll 4
    for (int k = 0; k < Gn; k++) {
        float bk = wk[(size_t)k * En + j];
        float bv = wv[(size_t)k * En + j];
        #pragma unroll
        for (int r = 0; r < 4; r++) {
            float rv = Rs[r * Gn + k];
            ak[r] = fmaf(rv, bk, ak[r]);
            av[r] = fmaf(rv, bv, av[r]);
        }
    }
    #pragma unroll
    for (int r = 0; r < 4; r++) {
        kws[((size_t)i * Nn + row0 + r) * En + j] = ak[r];
        vws[((size_t)i * Nn + row0 + r) * En + j] = av[r];
    }
}

// ---------------- generic batched row-strip GEMM (used for ow only) -------------
template <int R, bool RELU>
__global__ void gemm_rows_k(const float* __restrict__ A, long long sA,
                            const float* __restrict__ Bw, long long sB,
                            float* __restrict__ C, long long sC,
                            int M, int N, int K) {
    int i = blockIdx.y;
    A += (size_t)i * sA; Bw += (size_t)i * sB; C += (size_t)i * sC;
    int row0 = blockIdx.x * R;
    extern __shared__ float As[];
    for (int idx = threadIdx.x; idx < R * K; idx += blockDim.x)
        As[idx] = A[(size_t)(row0 + idx / K) * K + (idx % K)];
    __syncthreads();
    for (int j = threadIdx.x; j < N; j += blockDim.x) {
        float acc[R];
        #pragma unroll
        for (int r = 0; r < R; r++) acc[r] = 0.f;
        const float* bp = Bw + j;
        #pragma unroll 8
        for (int k = 0; k < K; k++) {
            float bv = bp[(size_t)k * N];
            #pragma unroll
            for (int r = 0; r < R; r++) acc[r] = fmaf(As[r * K + k], bv, acc[r]);
        }
        #pragma unroll
        for (int r = 0; r < R; r++) {
            float v = acc[r];
            if (RELU) v = fmaxf(v, 0.f);
            C[(size_t)(row0 + r) * N + j] = v;
        }
    }
}

// ---------------- collapsed attention: q rows repeat per batch ----------------
__global__ void attn_k(const float* __restrict__ compw, const float* __restrict__ wq,
                       const float* __restrict__ kmat, const float* __restrict__ vmat,
                       float* __restrict__ o4) {
    int i = blockIdx.y;
    int b = blockIdx.x & 3, h = blockIdx.x >> 2;
    const float* wqi = wq + (size_t)i * NCn * En;
    const float* km = kmat + (size_t)i * Nn * En;
    const float* vm = vmat + (size_t)i * Nn * En;
    __shared__ float q[DHn];
    __shared__ float p[Nn];
    __shared__ float red[4];
    int t = threadIdx.x;
    if (t < DHn) {
        float acc = 0.f;
        #pragma unroll
        for (int c = 0; c < NCn; c++)
            acc = fmaf(compw[b * NCn + c], wqi[(size_t)c * En + h * DHn + t], acc);
        q[t] = acc;
    }
    __syncthreads();
    const float scale = 0.17677669529663687f; // 1/sqrt(32)
    float sv[2];
    #pragma unroll
    for (int rep = 0; rep < 2; rep++) {
        int j = t + rep * 256;
        float acc = 0.f;
        const float* kr = km + (size_t)j * En + h * DHn;
        #pragma unroll
        for (int d = 0; d < DHn; d++) acc = fmaf(q[d], kr[d], acc);
        sv[rep] = acc * scale;
        p[j] = sv[rep];
    }
    __syncthreads();
    float lm = fmaxf(sv[0], sv[1]);
    #pragma unroll
    for (int o = 32; o > 0; o >>= 1) lm = fmaxf(lm, __shfl_xor(lm, o));
    if ((t & 63) == 0) red[t >> 6] = lm;
    __syncthreads();
    float m = fmaxf(fmaxf(red[0], red[1]), fmaxf(red[2], red[3]));
    __syncthreads();
    float ls = 0.f;
    #pragma unroll
    for (int rep = 0; rep < 2; rep++) {
        int j = t + rep * 256;
        float e = __expf(p[j] - m);
        p[j] = e;
        ls += e;
    }
    #pragma unroll
    for (int o = 32; o > 0; o >>= 1) ls += __shfl_xor(ls, o);
    if ((t & 63) == 0) red[t >> 6] = ls;
    __syncthreads();
    float s = red[0] + red[1] + red[2] + red[3];
    if (t < DHn) {
        float acc = 0.f;
        for (int j = 0; j < Nn; j++)
            acc = fmaf(p[j], vm[(size_t)j * En + h * DHn + t], acc);
        o4[((size_t)i * Bn + b) * En + h * DHn + t] = acc / s;
    }
}

// ---------------- out_exprs = relu(refw + ow[batch]) ----------------
__global__ void add_relu_k(const float* __restrict__ refw, const float* __restrict__ ow,
                           float* __restrict__ out) {
    int i = blockIdx.y, n = blockIdx.x, b = n >> 7;
    const float* rr = refw + ((size_t)i * Nn + n) * Gn;
    const float* oo = ow + ((size_t)i * Bn + b) * Gn;
    float* op = out + (size_t)i * (Nn * Gn) + (size_t)n * Gn;
    for (int j = threadIdx.x; j < Gn; j += blockDim.x)
        op[j] = fmaxf(rr[j] + oo[j], 0.f);
}

// ---------------- fused genes: gh = relu(e0@gw1); octe = gh@gw2 ----------------
__global__ void fused_genes_k(const float* __restrict__ e0, const float* __restrict__ gw1,
                              const float* __restrict__ gw2, float* __restrict__ gh,
                              float* __restrict__ octe) {
    int row0 = blockIdx.x * 4;
    __shared__ float As[4 * Gn];
    __shared__ float Hs[4 * En];
    int j = threadIdx.x;
    for (int idx = j; idx < 4 * Gn; idx += 256)
        As[idx] = e0[(size_t)row0 * Gn + idx];
    __syncthreads();
    {
        float acc[4] = {0.f, 0.f, 0.f, 0.f};
        #pragma unroll 8
        for (int k = 0; k < Gn; k++) {
            float bv = gw1[(size_t)k * En + j];
            #pragma unroll
            for (int r = 0; r < 4; r++) acc[r] = fmaf(As[r * Gn + k], bv, acc[r]);
        }
        #pragma unroll
        for (int r = 0; r < 4; r++) {
            float v = fmaxf(acc[r], 0.f);
            Hs[r * En + j] = v;
            gh[(size_t)(row0 + r) * En + j] = v;
        }
    }
    __syncthreads();
    if (j < NCn) {
        float acc[4] = {0.f, 0.f, 0.f, 0.f};
        #pragma unroll 8
        for (int k = 0; k < En; k++) {
            float bv = gw2[(size_t)k * NCn + j];
            #pragma unroll
            for (int r = 0; r < 4; r++) acc[r] = fmaf(Hs[r * En + k], bv, acc[r]);
        }
        #pragma unroll
        for (int r = 0; r < 4; r++) octe[(size_t)(row0 + r) * NCn + j] = acc[r];
    }
}

extern "C" void kernel_launch(void* const* d_in, const int* in_sizes, int n_in,
                              void* d_out, int out_size, void* d_ws, size_t ws_size,
                              hipStream_t stream) {
    const float* hd1     = (const float*)d_in[0];
    const float* h1      = (const float*)d_in[1];
    const float* ref     = (const float*)d_in[2];
    const float* embed_w = (const float*)d_in[3];
    const float* comp_w1 = (const float*)d_in[4];
    const float* comp_w2 = (const float*)d_in[5];
    const float* hist_w1 = (const float*)d_in[6];
    const float* hist_w2 = (const float*)d_in[7];
    const float* genes_w1= (const float*)d_in[8];
    const float* genes_w2= (const float*)d_in[9];
    const float* wref_w1 = (const float*)d_in[10];
    const float* wref_w2 = (const float*)d_in[11];
    const float* ca_wq   = (const float*)d_in[12];
    const float* ca_wk   = (const float*)d_in[13];
    const float* ca_wv   = (const float*)d_in[14];
    const float* ca_wo   = (const float*)d_in[15];
    const int*   mask    = (const int*)d_in[16];

    float* out = (float*)d_out;
    const size_t o_ct   = 0;                   // [512,16]
    const size_t o_e0   = 8192;                // [512,512] x3
    const size_t o_octe = 8192 + 3 * 262144;   // [512,16]
    const size_t o_gh   = o_octe + 8192;       // [512,256]
    const size_t o_comp = o_gh + 131072;       // [4,16]
    const size_t o_area = o_comp + 64;         // [512]

    // workspace layout (floats) — sums and bg must be contiguous (zeroed together)
    float* ws      = (float*)d_ws;
    float* sums    = ws;                     // 512*384 = 196608
    float* bg      = sums + 196608;          // 4*384   = 1536
    float* glob    = bg + 1536;              // 4*384
    float* areaf   = glob + 1536;            // 512
    float* emb     = areaf + 512;            // 512*256
    float* ep      = emb + 131072;           // 4*256
    float* compw   = ep + 1024;              // 4*16
    float* refw    = compw + 64;             // 3*512*512
    float* kws     = refw + 786432;          // 3*512*256
    float* vws     = kws + 393216;           // 3*512*256
    float* o4      = vws + 393216;           // 3*4*256
    float* ow      = o4 + 3072;              // 3*4*512

    zero_k<<<(196608 + 1536 + 255) / 256, 256, 0, stream>>>(sums, 196608 + 1536);
    area_k<<<Bn, 256, 0, stream>>>(mask, areaf, out + o_area);
    segreduce2_k<<<dim3(HWn / PCH, CF / TCg, Bn), 256, 0, stream>>>(hd1, h1, mask, sums, bg);
    glob_k<<<(Bn * CF + 255) / 256, 256, 0, stream>>>(sums, bg, glob);
    gemm_emb_k<<<Nn / 4, 256, 0, stream>>>(sums, glob, areaf, embed_w, emb);
    patch_mean_k<<<Bn, 256, 0, stream>>>(emb, ep);
    comp_mlp_k<<<Bn, 256, 0, stream>>>(ep, comp_w1, comp_w2, compw, out + o_comp);

    fused_hist_k<<<Nn / 4, 256, 0, stream>>>(emb, hist_w1, hist_w2, out + o_ct);
    fused_branch_k<<<dim3(Nn / 4, 3), 256, 0, stream>>>(emb, wref_w1, wref_w2, ref, refw);
    fused_kv_k<<<dim3(Nn / 4, 3), 256, 0, stream>>>(refw, ca_wk, ca_wv, kws, vws);
    attn_k<<<dim3(HEADSn * Bn, 3), 256, 0, stream>>>(compw, ca_wq, kws, vws, o4);
    gemm_rows_k<4, false><<<dim3(1, 3), 256, 4 * 256 * 4, stream>>>(
        o4, (long long)Bn * En, ca_wo, (long long)En * Gn, ow, (long long)Bn * Gn, Bn, Gn, En);
    add_relu_k<<<dim3(Nn, 3), 256, 0, stream>>>(refw, ow, out + o_e0);

    fused_genes_k<<<Nn / 4, 256, 0, stream>>>(out + o_e0, genes_w1, genes_w2,
                                              out + o_gh, out + o_octe);
}

// Round 4
// 710.446 us; speedup vs baseline: 1.7721x; 1.7721x over previous
//
#include <hip/hip_runtime.h>
#include <hip/hip_bf16.h>

#define Bn 4
#define C1n 256
#define C2n 128
#define CF 384
#define HWn 65536
#define Kc 128
#define Nn 512          // B*K
#define En 256
#define NCn 16
#define Gn 512
#define Rn 64
#define HEADSn 8
#define DHn 32

#define CHK 16          // chunks per image
#define PCH2 (HWn/CHK)  // 4096 pixels per chunk
#define TC2 32          // channels per block
#define NT 64           // pixels per tile

#define SCALE_F 1048576.0f
#define INV_SCALE (1.0f/1048576.0f)

typedef unsigned long long ull;

// ---------------- zero workspace accumulators (u64) ----------------
__global__ void zero_k(ull* __restrict__ p, int n) {
    int i = blockIdx.x * 256 + threadIdx.x;
    if (i < n) p[i] = 0ULL;
}

// ---------------- area histogram: grid (16 chunks, 4 batches) ----------------
__global__ __launch_bounds__(256) void area_k(const int* __restrict__ mask,
                                              int* __restrict__ area_i32) {
    int chunk = blockIdx.x, b = blockIdx.y;
    __shared__ int hist[4][129];
    int t = threadIdx.x, w = t >> 6;
    for (int i = t; i < 4 * 129; i += 256) ((int*)hist)[i] = 0;
    __syncthreads();
    const int* mp = mask + (size_t)b * HWn + chunk * PCH2;
    #pragma unroll
    for (int it = 0; it < 4; ++it) {
        int4 v = *(const int4*)(mp + it * 1024 + t * 4);
        atomicAdd(&hist[w][v.x], 1);
        atomicAdd(&hist[w][v.y], 1);
        atomicAdd(&hist[w][v.z], 1);
        atomicAdd(&hist[w][v.w], 1);
    }
    __syncthreads();
    if (t < 128) {
        int tot = hist[0][t+1] + hist[1][t+1] + hist[2][t+1] + hist[3][t+1];
        if (tot) atomicAdd(&area_i32[b * Kc + t], tot);
    }
}

// ---------------- segment reduce: native i64 fixed-point LDS atomics ----------
// grid (16 chunks, 12 ch-groups, 4 batches), 256 threads
__global__ __launch_bounds__(256) void segreduce3_k(
        const float* __restrict__ hd1, const float* __restrict__ h1,
        const int* __restrict__ mask,
        ull* __restrict__ sums64, ull* __restrict__ bg64) {
    int chunk = blockIdx.x, cg = blockIdx.y, b = blockIdx.z;
    int c0 = cg * TC2;
    const float* base = (c0 < C1n)
        ? hd1 + ((size_t)(b * C1n + c0)) * HWn
        : h1  + ((size_t)(b * C2n + (c0 - C1n))) * HWn;
    const int* mp = mask + (size_t)b * HWn + chunk * PCH2;

    __shared__ ull bins64[129 * TC2];          // 33 KB
    __shared__ float tile[NT * 33];            // 8.4 KB [px][33]
    __shared__ __align__(16) int idsh[NT];

    int t = threadIdx.x;
    int cL = t >> 3, l8 = t & 7;               // load mapping
    int cA = t & 31, pg = t >> 5;              // atomic mapping
    for (int i = t; i < 129 * TC2; i += 256) bins64[i] = 0ULL;
    __syncthreads();

    for (int tl = 0; tl < PCH2 / NT; ++tl) {
        int px0 = tl * NT;
        // coalesced global loads: 128-B segments per channel row
        float4 v0 = *(const float4*)(base + (size_t)cL * HWn + px0 + l8 * 4);
        float4 v1 = *(const float4*)(base + (size_t)cL * HWn + px0 + 32 + l8 * 4);
        if (t < 16) *(int4*)&idsh[t * 4] = *(const int4*)(mp + px0 + t * 4);
        // transpose into [px][33]
        int p0 = l8 * 4;
        tile[(p0 + 0) * 33 + cL] = v0.x;
        tile[(p0 + 1) * 33 + cL] = v0.y;
        tile[(p0 + 2) * 33 + cL] = v0.z;
        tile[(p0 + 3) * 33 + cL] = v0.w;
        tile[(32 + p0 + 0) * 33 + cL] = v1.x;
        tile[(32 + p0 + 1) * 33 + cL] = v1.y;
        tile[(32 + p0 + 2) * 33 + cL] = v1.z;
        tile[(32 + p0 + 3) * 33 + cL] = v1.w;
        __syncthreads();
        #pragma unroll
        for (int pp = 0; pp < 8; ++pp) {
            int p = pg * 8 + pp;
            int id = idsh[p];
            float v = tile[p * 33 + cA];
            long long qv = __float2ll_rn(v * SCALE_F);
            atomicAdd(&bins64[id * TC2 + cA], (ull)qv);   // native ds_add_u64
        }
        __syncthreads();
    }
    // flush: native global u64 atomics, coalesced
    for (int i = t; i < 129 * TC2; i += 256) {
        int cell = i >> 5, cc = i & 31;
        ull v = bins64[i];
        if (v) {
            if (cell == 0) atomicAdd(&bg64[b * CF + c0 + cc], v);
            else atomicAdd(&sums64[((size_t)(b * Kc + cell - 1)) * CF + c0 + cc], v);
        }
    }
}

// ---------------- glob + area conversion ----------------
__global__ void glob_k(const ull* __restrict__ sums64, const ull* __restrict__ bg64,
                       const int* __restrict__ area_i32, float* __restrict__ glob,
                       float* __restrict__ areaf, float* __restrict__ area_out) {
    int idx = blockIdx.x * 256 + threadIdx.x;
    if (idx < Bn * CF) {
        int b = idx / CF, c = idx - b * CF;
        long long s = (long long)bg64[idx];
        for (int cell = 0; cell < Kc; ++cell)
            s += (long long)sums64[((size_t)(b * Kc + cell)) * CF + c];
        glob[idx] = (float)s * (INV_SCALE / (float)HWn);
    }
    if (idx < Nn) {
        float a = (float)area_i32[idx];
        areaf[idx] = a;
        area_out[idx] = a;
    }
}

// ---------------- emb GEMM: [512,768]x[768,256], 2-row strips, K/4 waves ------
__global__ __launch_bounds__(256) void gemm_emb_k(
        const ull* __restrict__ sums64, const float* __restrict__ glob,
        const float* __restrict__ areaf, const float* __restrict__ Bw,
        float* __restrict__ C) {
    int row0 = blockIdx.x * 2;
    __shared__ float As[2 * 768];
    __shared__ float part[2048];
    __shared__ float rina[2];
    int t = threadIdx.x, lane = t & 63, w = t >> 6;
    if (t < 2) rina[t] = 1.f / fmaxf(areaf[row0 + t], 1.f);
    __syncthreads();
    for (int idx = t; idx < 2 * 768; idx += 256) {
        int r = idx / 768, k = idx - r * 768;
        int row = row0 + r;
        float v;
        if (k < CF) v = (float)(long long)sums64[(size_t)row * CF + k] * INV_SCALE * rina[r];
        else        v = glob[(row >> 7) * CF + (k - CF)];
        As[idx] = v;
    }
    __syncthreads();
    float acc[2][4] = {{0,0,0,0},{0,0,0,0}};
    const int KQ = 192;
    const float* bp = Bw + (size_t)(w * KQ) * 256 + lane * 4;
    #pragma unroll 8
    for (int k = 0; k < KQ; ++k) {
        float4 bv = *(const float4*)(bp + (size_t)k * 256);
        float a0 = As[w * KQ + k], a1 = As[768 + w * KQ + k];
        acc[0][0] = fmaf(a0, bv.x, acc[0][0]); acc[0][1] = fmaf(a0, bv.y, acc[0][1]);
        acc[0][2] = fmaf(a0, bv.z, acc[0][2]); acc[0][3] = fmaf(a0, bv.w, acc[0][3]);
        acc[1][0] = fmaf(a1, bv.x, acc[1][0]); acc[1][1] = fmaf(a1, bv.y, acc[1][1]);
        acc[1][2] = fmaf(a1, bv.z, acc[1][2]); acc[1][3] = fmaf(a1, bv.w, acc[1][3]);
    }
    *(float4*)&part[(w * 2 + 0) * 256 + lane * 4] = make_float4(acc[0][0], acc[0][1], acc[0][2], acc[0][3]);
    *(float4*)&part[(w * 2 + 1) * 256 + lane * 4] = make_float4(acc[1][0], acc[1][1], acc[1][2], acc[1][3]);
    __syncthreads();
    #pragma unroll
    for (int i2 = 0; i2 < 2; ++i2) {
        int idx = i2 * 256 + t, r = idx >> 8, c = idx & 255;
        float s = part[r*256+c] + part[(2+r)*256+c] + part[(4+r)*256+c] + part[(6+r)*256+c];
        C[(size_t)(row0 + r) * En + c] = s;
    }
}

// ---------------- per-batch mean of emb over K cells ----------------
__global__ void patch_mean_k(const float* __restrict__ emb, float* __restrict__ ep) {
    int b = blockIdx.x, j = threadIdx.x;
    float s = 0.f;
    for (int r = 0; r < Kc; r++) s += emb[(size_t)(b * Kc + r) * En + j];
    ep[b * En + j] = s * (1.f / (float)Kc);
}

// ---------------- comp MLP + softmax: one block per batch ----------------
__global__ void comp_mlp_k(const float* __restrict__ ep, const float* __restrict__ w1,
                           const float* __restrict__ w2, float* __restrict__ comp_ws,
                           float* __restrict__ comp_out) {
    int b = blockIdx.x, j = threadIdx.x;
    __shared__ float h[En];
    __shared__ float c[NCn];
    float acc = 0.f;
    #pragma unroll 8
    for (int k = 0; k < En; k++) acc = fmaf(ep[b * En + k], w1[(size_t)k * En + j], acc);
    h[j] = fmaxf(acc, 0.f);
    __syncthreads();
    if (j < NCn) {
        float a2 = 0.f;
        #pragma unroll 8
        for (int k = 0; k < En; k++) a2 = fmaf(h[k], w2[(size_t)k * NCn + j], a2);
        c[j] = a2;
    }
    __syncthreads();
    if (j == 0) {
        float m = c[0];
        for (int q = 1; q < NCn; q++) m = fmaxf(m, c[q]);
        float s = 0.f;
        for (int q = 0; q < NCn; q++) { c[q] = __expf(c[q] - m); s += c[q]; }
        float inv = 1.f / s;
        for (int q = 0; q < NCn; q++) c[q] *= inv;
    }
    __syncthreads();
    if (j < NCn) {
        comp_ws[b * NCn + j] = c[j];
        comp_out[b * NCn + j] = c[j];
    }
}

// ---------------- fused hist: out_ct = relu(emb@w1)@w2, 2-row strips ----------
__global__ __launch_bounds__(256) void fused_hist_k(
        const float* __restrict__ emb, const float* __restrict__ w1,
        const float* __restrict__ w2, float* __restrict__ out) {
    int row0 = blockIdx.x * 2;
    __shared__ float As[2 * En];
    __shared__ float part[2048];
    __shared__ float Hs[2 * En];
    int t = threadIdx.x, lane = t & 63, w = t >> 6;
    if (t < 128) *(float4*)&As[t * 4] = *(const float4*)(emb + (size_t)row0 * En + t * 4);
    __syncthreads();
    float acc[2][4] = {{0,0,0,0},{0,0,0,0}};
    const float* bp = w1 + (size_t)(w * 64) * 256 + lane * 4;
    #pragma unroll 8
    for (int k = 0; k < 64; ++k) {
        float4 bv = *(const float4*)(bp + (size_t)k * 256);
        float a0 = As[w * 64 + k], a1 = As[256 + w * 64 + k];
        acc[0][0] = fmaf(a0, bv.x, acc[0][0]); acc[0][1] = fmaf(a0, bv.y, acc[0][1]);
        acc[0][2] = fmaf(a0, bv.z, acc[0][2]); acc[0][3] = fmaf(a0, bv.w, acc[0][3]);
        acc[1][0] = fmaf(a1, bv.x, acc[1][0]); acc[1][1] = fmaf(a1, bv.y, acc[1][1]);
        acc[1][2] = fmaf(a1, bv.z, acc[1][2]); acc[1][3] = fmaf(a1, bv.w, acc[1][3]);
    }
    *(float4*)&part[(w * 2 + 0) * 256 + lane * 4] = make_float4(acc[0][0], acc[0][1], acc[0][2], acc[0][3]);
    *(float4*)&part[(w * 2 + 1) * 256 + lane * 4] = make_float4(acc[1][0], acc[1][1], acc[1][2], acc[1][3]);
    __syncthreads();
    #pragma unroll
    for (int i2 = 0; i2 < 2; ++i2) {
        int idx = i2 * 256 + t, r = idx >> 8, c = idx & 255;
        float s = part[r*256+c] + part[(2+r)*256+c] + part[(4+r)*256+c] + part[(6+r)*256+c];
        Hs[r * 256 + c] = fmaxf(s, 0.f);
    }
    __syncthreads();
    if (t < 32) {
        int r = t >> 4, j = t & 15;
        float a2 = 0.f;
        #pragma unroll 8
        for (int k = 0; k < En; k++) a2 = fmaf(Hs[r * 256 + k], w2[(size_t)k * NCn + j], a2);
        out[(size_t)(row0 + r) * NCn + j] = a2;
    }
}

// ---------------- fused branch: relu(emb@w1)@w2 -> softmax -> @ref ------------
__global__ __launch_bounds__(256) void fused_branch_k(
        const float* __restrict__ emb, const float* __restrict__ wref_w1,
        const float* __restrict__ wref_w2, const float* __restrict__ ref,
        float* __restrict__ refw) {
    int i = blockIdx.y, row0 = blockIdx.x * 2;
    const float* w1 = wref_w1 + (size_t)i * En * En;
    const float* w2 = wref_w2 + (size_t)i * En * Rn;
    __shared__ float As[2 * En];
    __shared__ float part[2048];
    __shared__ float Hs[2 * En];
    __shared__ float RW[2 * Rn];
    int t = threadIdx.x, lane = t & 63, w = t >> 6;
    if (t < 128) *(float4*)&As[t * 4] = *(const float4*)(emb + (size_t)row0 * En + t * 4);
    __syncthreads();
    {   // stage1: Hs = relu(A @ w1)  K=256
        float acc[2][4] = {{0,0,0,0},{0,0,0,0}};
        const float* bp = w1 + (size_t)(w * 64) * 256 + lane * 4;
        #pragma unroll 8
        for (int k = 0; k < 64; ++k) {
            float4 bv = *(const float4*)(bp + (size_t)k * 256);
            float a0 = As[w * 64 + k], a1 = As[256 + w * 64 + k];
            acc[0][0] = fmaf(a0, bv.x, acc[0][0]); acc[0][1] = fmaf(a0, bv.y, acc[0][1]);
            acc[0][2] = fmaf(a0, bv.z, acc[0][2]); acc[0][3] = fmaf(a0, bv.w, acc[0][3]);
            acc[1][0] = fmaf(a1, bv.x, acc[1][0]); acc[1][1] = fmaf(a1, bv.y, acc[1][1]);
            acc[1][2] = fmaf(a1, bv.z, acc[1][2]); acc[1][3] = fmaf(a1, bv.w, acc[1][3]);
        }
        *(float4*)&part[(w * 2 + 0) * 256 + lane * 4] = make_float4(acc[0][0], acc[0][1], acc[0][2], acc[0][3]);
        *(float4*)&part[(w * 2 + 1) * 256 + lane * 4] = make_float4(acc[1][0], acc[1][1], acc[1][2], acc[1][3]);
    }
    __syncthreads();
    #pragma unroll
    for (int i2 = 0; i2 < 2; ++i2) {
        int idx = i2 * 256 + t, r = idx >> 8, c = idx & 255;
        float s = part[r*256+c] + part[(2+r)*256+c] + part[(4+r)*256+c] + part[(6+r)*256+c];
        Hs[r * 256 + c] = fmaxf(s, 0.f);
    }
    __syncthreads();
    {   // stage2: rw = Hs @ w2  K=256, N=64
        float a0 = 0.f, a1 = 0.f;
        const float* bp = w2 + (size_t)(w * 64) * 64 + lane;
        #pragma unroll 8
        for (int k = 0; k < 64; ++k) {
            float bv = bp[(size_t)k * 64];
            a0 = fmaf(Hs[w * 64 + k], bv, a0);
            a1 = fmaf(Hs[256 + w * 64 + k], bv, a1);
        }
        part[(w * 2 + 0) * 64 + lane] = a0;
        part[(w * 2 + 1) * 64 + lane] = a1;
    }
    __syncthreads();
    if (t < 128) {
        int r = t >> 6, c = t & 63;
        RW[r * 64 + c] = part[r*64+c] + part[(2+r)*64+c] + part[(4+r)*64+c] + part[(6+r)*64+c];
    }
    __syncthreads();
    if (w < 2) {   // softmax over 64, wave w = row w
        float v = RW[w * 64 + lane];
        float m = v;
        #pragma unroll
        for (int o = 32; o > 0; o >>= 1) m = fmaxf(m, __shfl_xor(m, o));
        float e = __expf(v - m), s = e;
        #pragma unroll
        for (int o = 32; o > 0; o >>= 1) s += __shfl_xor(s, o);
        RW[w * 64 + lane] = e / s;
    }
    __syncthreads();
    {   // stage4: refw strip = RW @ ref  K=64, N=512, K-halves over t>>7
        int q = t & 127, kh = t >> 7;
        float acc[2][4] = {{0,0,0,0},{0,0,0,0}};
        const float* bp = ref + (size_t)(kh * 32) * 512 + q * 4;
        #pragma unroll 8
        for (int k = 0; k < 32; ++k) {
            float4 bv = *(const float4*)(bp + (size_t)k * 512);
            float a0 = RW[kh * 32 + k], a1 = RW[64 + kh * 32 + k];
            acc[0][0] = fmaf(a0, bv.x, acc[0][0]); acc[0][1] = fmaf(a0, bv.y, acc[0][1]);
            acc[0][2] = fmaf(a0, bv.z, acc[0][2]); acc[0][3] = fmaf(a0, bv.w, acc[0][3]);
            acc[1][0] = fmaf(a1, bv.x, acc[1][0]); acc[1][1] = fmaf(a1, bv.y, acc[1][1]);
            acc[1][2] = fmaf(a1, bv.z, acc[1][2]); acc[1][3] = fmaf(a1, bv.w, acc[1][3]);
        }
        *(float4*)&part[(kh * 2 + 0) * 512 + q * 4] = make_float4(acc[0][0], acc[0][1], acc[0][2], acc[0][3]);
        *(float4*)&part[(kh * 2 + 1) * 512 + q * 4] = make_float4(acc[1][0], acc[1][1], acc[1][2], acc[1][3]);
    }
    __syncthreads();
    float* op = refw + ((size_t)i * Nn + row0) * Gn;
    #pragma unroll
    for (int i2 = 0; i2 < 4; ++i2) {
        int idx = i2 * 256 + t, r = idx >> 9, c = idx & 511;
        op[(size_t)r * Gn + c] = part[r * 512 + c] + part[(2 + r) * 512 + c];
    }
}

// ---------------- fused K/V projections ----------------
__global__ __launch_bounds__(256) void fused_kv_k(
        const float* __restrict__ refw, const float* __restrict__ ca_wk,
        const float* __restrict__ ca_wv, float* __restrict__ kws,
        float* __restrict__ vws) {
    int i = blockIdx.y, row0 = blockIdx.x * 2;
    const float* wk = ca_wk + (size_t)i * Gn * En;
    const float* wv = ca_wv + (size_t)i * Gn * En;
    __shared__ float As[2 * Gn];
    __shared__ float part[2048];
    int t = threadIdx.x, lane = t & 63, w = t >> 6;
    const float* rp = refw + ((size_t)i * Nn + row0) * Gn;
    *(float4*)&As[t * 4] = *(const float4*)(rp + t * 4);
    __syncthreads();
    int which = w >> 1, half = w & 1;
    const float* Bp = (which ? wv : wk) + (size_t)(half * 256) * En + lane * 4;
    float acc[2][4] = {{0,0,0,0},{0,0,0,0}};
    #pragma unroll 8
    for (int k = 0; k < 256; ++k) {
        float4 bv = *(const float4*)(Bp + (size_t)k * En);
        float a0 = As[half * 256 + k], a1 = As[512 + half * 256 + k];
        acc[0][0] = fmaf(a0, bv.x, acc[0][0]); acc[0][1] = fmaf(a0, bv.y, acc[0][1]);
        acc[0][2] = fmaf(a0, bv.z, acc[0][2]); acc[0][3] = fmaf(a0, bv.w, acc[0][3]);
        acc[1][0] = fmaf(a1, bv.x, acc[1][0]); acc[1][1] = fmaf(a1, bv.y, acc[1][1]);
        acc[1][2] = fmaf(a1, bv.z, acc[1][2]); acc[1][3] = fmaf(a1, bv.w, acc[1][3]);
    }
    *(float4*)&part[(w * 2 + 0) * 256 + lane * 4] = make_float4(acc[0][0], acc[0][1], acc[0][2], acc[0][3]);
    *(float4*)&part[(w * 2 + 1) * 256 + lane * 4] = make_float4(acc[1][0], acc[1][1], acc[1][2], acc[1][3]);
    __syncthreads();
    #pragma unroll
    for (int i2 = 0; i2 < 2; ++i2) {
        int idx = i2 * 256 + t, r = idx >> 8, c = idx & 255;
        float sk = part[r * 256 + c] + part[(2 + r) * 256 + c];
        float sv = part[(4 + r) * 256 + c] + part[(6 + r) * 256 + c];
        kws[((size_t)i * Nn + row0 + r) * En + c] = sk;
        vws[((size_t)i * Nn + row0 + r) * En + c] = sv;
    }
}

// ---------------- generic batched row-strip GEMM (ow only) ----------------
template <int R, bool RELU>
__global__ void gemm_rows_k(const float* __restrict__ A, long long sA,
                            const float* __restrict__ Bw, long long sB,
                            float* __restrict__ C, long long sC,
                            int M, int N, int K) {
    int i = blockIdx.y;
    A += (size_t)i * sA; Bw += (size_t)i * sB; C += (size_t)i * sC;
    int row0 = blockIdx.x * R;
    extern __shared__ float As[];
    for (int idx = threadIdx.x; idx < R * K; idx += blockDim.x)
        As[idx] = A[(size_t)(row0 + idx / K) * K + (idx % K)];
    __syncthreads();
    for (int j = threadIdx.x; j < N; j += blockDim.x) {
        float acc[R];
        #pragma unroll
        for (int r = 0; r < R; r++) acc[r] = 0.f;
        const float* bp = Bw + j;
        #pragma unroll 8
        for (int k = 0; k < K; k++) {
            float bv = bp[(size_t)k * N];
            #pragma unroll
            for (int r = 0; r < R; r++) acc[r] = fmaf(As[r * K + k], bv, acc[r]);
        }
        #pragma unroll
        for (int r = 0; r < R; r++) {
            float v = acc[r];
            if (RELU) v = fmaxf(v, 0.f);
            C[(size_t)(row0 + r) * N + j] = v;
        }
    }
}

// ---------------- collapsed attention ----------------
__global__ __launch_bounds__(256) void attn_k(
        const float* __restrict__ compw, const float* __restrict__ wq,
        const float* __restrict__ kmat, const float* __restrict__ vmat,
        float* __restrict__ o4) {
    int i = blockIdx.y, b = blockIdx.x & 3, h = blockIdx.x >> 2;
    const float* wqi = wq + (size_t)i * NCn * En;
    const float* km = kmat + (size_t)i * Nn * En;
    const float* vm = vmat + (size_t)i * Nn * En;
    __shared__ float q[DHn];
    __shared__ float p[Nn];
    __shared__ float red[4];
    __shared__ float pvp[8][33];
    int t = threadIdx.x;
    if (t < DHn) {
        float acc = 0.f;
        #pragma unroll
        for (int c = 0; c < NCn; c++)
            acc = fmaf(compw[b * NCn + c], wqi[(size_t)c * En + h * DHn + t], acc);
        q[t] = acc;
    }
    __syncthreads();
    const float scale = 0.17677669529663687f;
    float sv0, sv1;
    {
        const float* kr = km + (size_t)t * En + h * DHn;
        float a = 0.f;
        #pragma unroll
        for (int d = 0; d < DHn; d++) a = fmaf(q[d], kr[d], a);
        sv0 = a * scale;
        kr += (size_t)256 * En;
        a = 0.f;
        #pragma unroll
        for (int d = 0; d < DHn; d++) a = fmaf(q[d], kr[d], a);
        sv1 = a * scale;
    }
    float lm = fmaxf(sv0, sv1);
    #pragma unroll
    for (int o = 32; o > 0; o >>= 1) lm = fmaxf(lm, __shfl_xor(lm, o));
    if ((t & 63) == 0) red[t >> 6] = lm;
    __syncthreads();
    float m = fmaxf(fmaxf(red[0], red[1]), fmaxf(red[2], red[3]));
    __syncthreads();
    float e0 = __expf(sv0 - m), e1 = __expf(sv1 - m);
    p[t] = e0; p[t + 256] = e1;
    float ls = e0 + e1;
    #pragma unroll
    for (int o = 32; o > 0; o >>= 1) ls += __shfl_xor(ls, o);
    if ((t & 63) == 0) red[t >> 6] = ls;
    __syncthreads();
    float ssum = red[0] + red[1] + red[2] + red[3];
    int d = t & 31, seg = t >> 5;
    float acc = 0.f;
    const float* vp = vm + (size_t)(seg * 64) * En + h * DHn + d;
    #pragma unroll 8
    for (int j = 0; j < 64; ++j) acc = fmaf(p[seg * 64 + j], vp[(size_t)j * En], acc);
    pvp[seg][d] = acc;
    __syncthreads();
    if (t < DHn) {
        float o = 0.f;
        #pragma unroll
        for (int s8 = 0; s8 < 8; ++s8) o += pvp[s8][t];
        o4[((size_t)i * Bn + b) * En + h * DHn + t] = o / ssum;
    }
}

// ---------------- out_exprs = relu(refw + ow[batch]), vectorized --------------
__global__ void add_relu_k(const float* __restrict__ refw, const float* __restrict__ ow,
                           float* __restrict__ out) {
    int i = blockIdx.y, n = blockIdx.x, b = n >> 7;
    const float4* rr = (const float4*)(refw + ((size_t)i * Nn + n) * Gn);
    const float4* oo = (const float4*)(ow + ((size_t)i * Bn + b) * Gn);
    float4* op = (float4*)(out + (size_t)i * (Nn * Gn) + (size_t)n * Gn);
    int j = threadIdx.x;
    float4 a = rr[j], o = oo[j];
    op[j] = make_float4(fmaxf(a.x + o.x, 0.f), fmaxf(a.y + o.y, 0.f),
                        fmaxf(a.z + o.z, 0.f), fmaxf(a.w + o.w, 0.f));
}

// ---------------- fused genes: gh = relu(e0@gw1); octe = gh@gw2 ---------------
__global__ __launch_bounds__(256) void fused_genes_k(
        const float* __restrict__ e0, const float* __restrict__ gw1,
        const float* __restrict__ gw2, float* __restrict__ gh,
        float* __restrict__ octe) {
    int row0 = blockIdx.x * 2;
    __shared__ float As[2 * Gn];
    __shared__ float part[2048];
    __shared__ float Hs[2 * En];
    int t = threadIdx.x, lane = t & 63, w = t >> 6;
    *(float4*)&As[t * 4] = *(const float4*)(e0 + (size_t)row0 * Gn + t * 4);
    __syncthreads();
    {
        float acc[2][4] = {{0,0,0,0},{0,0,0,0}};
        const float* bp = gw1 + (size_t)(w * 128) * 256 + lane * 4;
        #pragma unroll 8
        for (int k = 0; k < 128; ++k) {
            float4 bv = *(const float4*)(bp + (size_t)k * 256);
            float a0 = As[w * 128 + k], a1 = As[512 + w * 128 + k];
            acc[0][0] = fmaf(a0, bv.x, acc[0][0]); acc[0][1] = fmaf(a0, bv.y, acc[0][1]);
            acc[0][2] = fmaf(a0, bv.z, acc[0][2]); acc[0][3] = fmaf(a0, bv.w, acc[0][3]);
            acc[1][0] = fmaf(a1, bv.x, acc[1][0]); acc[1][1] = fmaf(a1, bv.y, acc[1][1]);
            acc[1][2] = fmaf(a1, bv.z, acc[1][2]); acc[1][3] = fmaf(a1, bv.w, acc[1][3]);
        }
        *(float4*)&part[(w * 2 + 0) * 256 + lane * 4] = make_float4(acc[0][0], acc[0][1], acc[0][2], acc[0][3]);
        *(float4*)&part[(w * 2 + 1) * 256 + lane * 4] = make_float4(acc[1][0], acc[1][1], acc[1][2], acc[1][3]);
    }
    __syncthreads();
    #pragma unroll
    for (int i2 = 0; i2 < 2; ++i2) {
        int idx = i2 * 256 + t, r = idx >> 8, c = idx & 255;
        float s = part[r*256+c] + part[(2+r)*256+c] + part[(4+r)*256+c] + part[(6+r)*256+c];
        float v = fmaxf(s, 0.f);
        Hs[r * 256 + c] = v;
        gh[(size_t)(row0 + r) * En + c] = v;
    }
    __syncthreads();
    if (t < 32) {
        int r = t >> 4, j = t & 15;
        float a2 = 0.f;
        #pragma unroll 8
        for (int k = 0; k < En; k++) a2 = fmaf(Hs[r * 256 + k], gw2[(size_t)k * NCn + j], a2);
        octe[(size_t)(row0 + r) * NCn + j] = a2;
    }
}

extern "C" void kernel_launch(void* const* d_in, const int* in_sizes, int n_in,
                              void* d_out, int out_size, void* d_ws, size_t ws_size,
                              hipStream_t stream) {
    const float* hd1     = (const float*)d_in[0];
    const float* h1      = (const float*)d_in[1];
    const float* ref     = (const float*)d_in[2];
    const float* embed_w = (const float*)d_in[3];
    const float* comp_w1 = (const float*)d_in[4];
    const float* comp_w2 = (const float*)d_in[5];
    const float* hist_w1 = (const float*)d_in[6];
    const float* hist_w2 = (const float*)d_in[7];
    const float* genes_w1= (const float*)d_in[8];
    const float* genes_w2= (const float*)d_in[9];
    const float* wref_w1 = (const float*)d_in[10];
    const float* wref_w2 = (const float*)d_in[11];
    const float* ca_wq   = (const float*)d_in[12];
    const float* ca_wk   = (const float*)d_in[13];
    const float* ca_wv   = (const float*)d_in[14];
    const float* ca_wo   = (const float*)d_in[15];
    const int*   mask    = (const int*)d_in[16];

    float* out = (float*)d_out;
    const size_t o_ct   = 0;
    const size_t o_e0   = 8192;
    const size_t o_octe = 8192 + 3 * 262144;
    const size_t o_gh   = o_octe + 8192;
    const size_t o_comp = o_gh + 131072;
    const size_t o_area = o_comp + 64;

    // workspace: [ sums64 (196608) | bg64 (1536) | area_i32 (512 ints = 256 ull) ]
    ull* sums64 = (ull*)d_ws;                    // 196608 ull
    ull* bg64   = sums64 + 196608;               // 1536 ull
    int* area_i32 = (int*)(bg64 + 1536);         // 512 ints = 256 ull
    float* fbase = (float*)(sums64 + 196608 + 1536 + 256);
    float* glob  = fbase;                        // 1536
    float* areaf = glob + 1536;                  // 512
    float* emb   = areaf + 512;                  // 131072
    float* ep    = emb + 131072;                 // 1024
    float* compw = ep + 1024;                    // 64
    float* refw  = compw + 64;                   // 786432
    float* kws   = refw + 786432;                // 393216
    float* vws   = kws + 393216;                 // 393216
    float* o4    = vws + 393216;                 // 3072
    float* ow    = o4 + 3072;                    // 6144

    const int nzero = 196608 + 1536 + 256;       // u64 elements
    zero_k<<<(nzero + 255) / 256, 256, 0, stream>>>(sums64, nzero);
    area_k<<<dim3(CHK, Bn), 256, 0, stream>>>(mask, area_i32);
    segreduce3_k<<<dim3(CHK, CF / TC2, Bn), 256, 0, stream>>>(hd1, h1, mask, sums64, bg64);
    glob_k<<<6, 256, 0, stream>>>(sums64, bg64, area_i32, glob, areaf, out + o_area);
    gemm_emb_k<<<Nn / 2, 256, 0, stream>>>(sums64, glob, areaf, embed_w, emb);
    patch_mean_k<<<Bn, 256, 0, stream>>>(emb, ep);
    comp_mlp_k<<<Bn, 256, 0, stream>>>(ep, comp_w1, comp_w2, compw, out + o_comp);

    fused_hist_k<<<Nn / 2, 256, 0, stream>>>(emb, hist_w1, hist_w2, out + o_ct);
    fused_branch_k<<<dim3(Nn / 2, 3), 256, 0, stream>>>(emb, wref_w1, wref_w2, ref, refw);
    fused_kv_k<<<dim3(Nn / 2, 3), 256, 0, stream>>>(refw, ca_wk, ca_wv, kws, vws);
    attn_k<<<dim3(HEADSn * Bn, 3), 256, 0, stream>>>(compw, ca_wq, kws, vws, o4);
    gemm_rows_k<4, false><<<dim3(1, 3), 256, 4 * 256 * 4, stream>>>(
        o4, (long long)Bn * En, ca_wo, (long long)En * Gn, ow, (long long)Bn * Gn, Bn, Gn, En);
    add_relu_k<<<dim3(Nn, 3), 128, 0, stream>>>(refw, ow, out + o_e0);

    fused_genes_k<<<Nn / 2, 256, 0, stream>>>(out + o_e0, genes_w1, genes_w2,
                                              out + o_gh, out + o_octe);
}